// Round 1
// baseline (1341.969 us; speedup 1.0000x reference)
//
#include <hip/hip_runtime.h>

// Transformer layer, bf16 MFMA compute, fp32 I/O.
// B=2 T=2048 E=2048 H=16 DH=128 FFN=8192. Needs ~235MB workspace.

#define T_SEQ 2048
#define E_DIM 2048
#define N_HEAD 16
#define D_HEAD 128
#define FFN_DIM 8192
#define M_ROWS 4096  // B*T

typedef unsigned short u16;
typedef short short8 __attribute__((ext_vector_type(8)));
typedef float f32x4 __attribute__((ext_vector_type(4)));

#define DEV __device__ __forceinline__

DEV u16 f2bf(float f) {
  unsigned u = __float_as_uint(f);
  u += 0x7fffu + ((u >> 16) & 1u);
  return (u16)(u >> 16);
}
DEV float bf2f(u16 h) { return __uint_as_float(((unsigned)h) << 16); }

DEV void async16(void* lds, const void* g) {
  __builtin_amdgcn_global_load_lds((const __attribute__((address_space(1))) void*)g,
                                   (__attribute__((address_space(3))) void*)lds, 16, 0, 0);
}

// ---------------- LayerNorm: fp32 [rows][E] -> bf16 -----------------
__global__ __launch_bounds__(256) void ln_kernel(const float* __restrict__ x,
                                                 const float* __restrict__ gw,
                                                 const float* __restrict__ bw,
                                                 u16* __restrict__ out) {
  int row = blockIdx.x;
  int t = threadIdx.x;
  const float4* xr = (const float4*)(x + (size_t)row * E_DIM);
  float4 a = xr[t], c = xr[t + 256];
  float s = a.x + a.y + a.z + a.w + c.x + c.y + c.z + c.w;
  float q = a.x * a.x + a.y * a.y + a.z * a.z + a.w * a.w +
            c.x * c.x + c.y * c.y + c.z * c.z + c.w * c.w;
  for (int off = 32; off > 0; off >>= 1) {
    s += __shfl_down(s, off);
    q += __shfl_down(q, off);
  }
  __shared__ float red[8];
  if ((t & 63) == 0) { red[(t >> 6) * 2] = s; red[(t >> 6) * 2 + 1] = q; }
  __syncthreads();
  s = red[0] + red[2] + red[4] + red[6];
  q = red[1] + red[3] + red[5] + red[7];
  float mu = s * (1.f / E_DIM);
  float rs = rsqrtf(q * (1.f / E_DIM) - mu * mu + 1e-5f);
  const float4* g4 = (const float4*)gw;
  const float4* b4 = (const float4*)bw;
  float4 g0 = g4[t], g1v = g4[t + 256], e0 = b4[t], e1 = b4[t + 256];
  ushort4 o0, o1;
  o0.x = f2bf((a.x - mu) * rs * g0.x + e0.x);
  o0.y = f2bf((a.y - mu) * rs * g0.y + e0.y);
  o0.z = f2bf((a.z - mu) * rs * g0.z + e0.z);
  o0.w = f2bf((a.w - mu) * rs * g0.w + e0.w);
  o1.x = f2bf((c.x - mu) * rs * g1v.x + e1.x);
  o1.y = f2bf((c.y - mu) * rs * g1v.y + e1.y);
  o1.z = f2bf((c.z - mu) * rs * g1v.z + e1.z);
  o1.w = f2bf((c.w - mu) * rs * g1v.w + e1.w);
  ((ushort4*)(out + (size_t)row * E_DIM))[t] = o0;
  ((ushort4*)(out + (size_t)row * E_DIM))[t + 256] = o1;
}

// ------- convert+transpose: fp32 W[K][N] -> bf16 WT[N][K] -----------
__global__ __launch_bounds__(256) void cvt_t_kernel(const float* __restrict__ W,
                                                    u16* __restrict__ WT,
                                                    int Kd, int Nd) {
  __shared__ float tile[32][33];
  int tx = threadIdx.x, ty = threadIdx.y;
  int n0 = blockIdx.x * 32, k0 = blockIdx.y * 32;
#pragma unroll
  for (int i = 0; i < 4; i++)
    tile[ty + i * 8][tx] = W[(size_t)(k0 + ty + i * 8) * Nd + n0 + tx];
  __syncthreads();
#pragma unroll
  for (int i = 0; i < 4; i++)
    WT[(size_t)(n0 + ty + i * 8) * Kd + k0 + tx] = f2bf(tile[tx][ty + i * 8]);
}

// ------- transpose V per batch: bf16 [B*T][E] -> [B][E][T] ----------
__global__ __launch_bounds__(256) void transpose_v_kernel(const u16* __restrict__ v,
                                                          u16* __restrict__ vt) {
  __shared__ u16 tile[32][33];
  int tx = threadIdx.x, ty = threadIdx.y;
  int b = blockIdx.z;
  int t0 = blockIdx.x * 32, e0 = blockIdx.y * 32;
#pragma unroll
  for (int i = 0; i < 4; i++)
    tile[ty + i * 8][tx] = v[(size_t)(b * T_SEQ + t0 + ty + i * 8) * E_DIM + e0 + tx];
  __syncthreads();
#pragma unroll
  for (int i = 0; i < 4; i++)
    vt[((size_t)b * E_DIM + e0 + ty + i * 8) * T_SEQ + t0 + tx] = tile[tx][ty + i * 8];
}

// ----------------- GEMM: C[M][N] = A[M][K] * BT[N][K]^T -------------
// MODE 0: write bf16 C.
// MODE 1: Cout(float) = Extra(float resid) + acc.
// MODE 2: Cout(bf16)  = silu(Extra bf16) * acc   (SwiGLU; Extra may alias Cout)
template <int MODE>
__global__ __launch_bounds__(256, 2) void gemm_bt(const u16* __restrict__ A,
                                                  const u16* __restrict__ BT,
                                                  void* Cout, const void* Extra,
                                                  int N, int K) {
  __shared__ u16 As[128 * 32];
  __shared__ u16 Bs[128 * 32];
  const int t = threadIdx.x;
  const int l = t & 63, w = t >> 6;
  const int wr = w >> 1, wc = w & 1;
  const int lq = l & 15, g = l >> 4;
  const size_t bm = (size_t)blockIdx.y * 128, bn = (size_t)blockIdx.x * 128;

  const u16* Ap = A + (bm + (t >> 2)) * (size_t)K + (t & 3) * 8;
  const u16* Bp = BT + (bn + (t >> 2)) * (size_t)K + (t & 3) * 8;
  u16* as_dst = As + w * 512;  // wave-uniform; HW adds lane*16B
  u16* bs_dst = Bs + w * 512;

  f32x4 acc[4][4] = {};

  for (int k0 = 0; k0 < K; k0 += 32) {
    async16(as_dst, Ap + k0);
    async16(as_dst + 2048, Ap + (size_t)64 * K + k0);
    async16(bs_dst, Bp + k0);
    async16(bs_dst + 2048, Bp + (size_t)64 * K + k0);
    __syncthreads();
    short8 af[4], bf[4];
#pragma unroll
    for (int m = 0; m < 4; m++)
      af[m] = *(const short8*)(As + (wr * 64 + m * 16 + lq) * 32 + g * 8);
#pragma unroll
    for (int n = 0; n < 4; n++)
      bf[n] = *(const short8*)(Bs + (wc * 64 + n * 16 + lq) * 32 + g * 8);
#pragma unroll
    for (int m = 0; m < 4; m++)
#pragma unroll
      for (int n = 0; n < 4; n++)
        acc[m][n] = __builtin_amdgcn_mfma_f32_16x16x32_bf16(af[m], bf[n], acc[m][n], 0, 0, 0);
    __syncthreads();
  }

#pragma unroll
  for (int m = 0; m < 4; m++) {
    size_t row = bm + wr * 64 + m * 16 + 4 * g;
#pragma unroll
    for (int n = 0; n < 4; n++) {
      size_t col = bn + wc * 64 + n * 16 + lq;
#pragma unroll
      for (int r = 0; r < 4; r++) {
        size_t idx = (row + r) * (size_t)N + col;
        if constexpr (MODE == 0) {
          ((u16*)Cout)[idx] = f2bf(acc[m][n][r]);
        } else if constexpr (MODE == 1) {
          ((float*)Cout)[idx] = ((const float*)Extra)[idx] + acc[m][n][r];
        } else {
          float a = bf2f(((const u16*)Extra)[idx]);
          float sil = a / (1.f + exp2f(-1.4426950408889634f * a));
          ((u16*)Cout)[idx] = f2bf(sil * acc[m][n][r]);
        }
      }
    }
  }
}

// ----------------- causal flash attention ---------------------------
// grid (T/64, B*H); 4 waves/block, each wave owns 16 q-rows.
// Q,K natural [B*T][E]; VT [B][E][T]; out CTX bf16 [B*T][E].
__global__ __launch_bounds__(256, 3) void attn_kernel(const u16* __restrict__ Q,
                                                      const u16* __restrict__ Kb,
                                                      const u16* __restrict__ VT,
                                                      u16* __restrict__ CTX) {
  __shared__ u16 P_all[4][16 * 40];  // per-wave padded P tile
  const int t = threadIdx.x;
  const int w = t >> 6, l = t & 63, g = l >> 4, lq = l & 15;
  u16* P = P_all[w];
  const int q0 = (blockIdx.x * 4 + w) * 16;
  const int bh = blockIdx.y, b = bh >> 4, h = bh & 15;
  const u16* qp = Q + (size_t)b * T_SEQ * E_DIM + h * D_HEAD;
  const u16* kp = Kb + (size_t)b * T_SEQ * E_DIM + h * D_HEAD;
  const u16* vp = VT + ((size_t)b * E_DIM + h * D_HEAD) * T_SEQ;

  short8 qf[4];
#pragma unroll
  for (int ks = 0; ks < 4; ks++)
    qf[ks] = *(const short8*)(qp + (size_t)(q0 + lq) * E_DIM + ks * 32 + g * 8);

  f32x4 acc[8] = {};
  float m2[4], ls[4];
#pragma unroll
  for (int r = 0; r < 4; r++) { m2[r] = -1e30f; ls[r] = 0.f; }
  const float sc = 0.08838834764831845f * 1.4426950408889634f;  // 1/sqrt(128)*log2e

  for (int kv0 = 0; kv0 < q0 + 16; kv0 += 32) {
    f32x4 s0 = {0.f, 0.f, 0.f, 0.f}, s1 = {0.f, 0.f, 0.f, 0.f};
#pragma unroll
    for (int ks = 0; ks < 4; ks++) {
      short8 kf = *(const short8*)(kp + (size_t)(kv0 + lq) * E_DIM + ks * 32 + g * 8);
      s0 = __builtin_amdgcn_mfma_f32_16x16x32_bf16(qf[ks], kf, s0, 0, 0, 0);
    }
#pragma unroll
    for (int ks = 0; ks < 4; ks++) {
      short8 kf = *(const short8*)(kp + (size_t)(kv0 + 16 + lq) * E_DIM + ks * 32 + g * 8);
      s1 = __builtin_amdgcn_mfma_f32_16x16x32_bf16(qf[ks], kf, s1, 0, 0, 0);
    }
    float sv[2][4];
#pragma unroll
    for (int r = 0; r < 4; r++) { sv[0][r] = s0[r] * sc; sv[1][r] = s1[r] * sc; }
    if (kv0 + 32 > q0) {  // tile crosses the diagonal: mask kv > q
#pragma unroll
      for (int c = 0; c < 2; c++)
#pragma unroll
        for (int r = 0; r < 4; r++)
          if (kv0 + c * 16 + lq > q0 + 4 * g + r) sv[c][r] = -1e30f;
    }
    float mx[4];
#pragma unroll
    for (int r = 0; r < 4; r++) mx[r] = fmaxf(sv[0][r], sv[1][r]);
#pragma unroll
    for (int off = 1; off < 16; off <<= 1)
#pragma unroll
      for (int r = 0; r < 4; r++) mx[r] = fmaxf(mx[r], __shfl_xor(mx[r], off));
    float p0[4], p1[4];
#pragma unroll
    for (int r = 0; r < 4; r++) {
      float mn = fmaxf(m2[r], mx[r]);
      float sca = exp2f(m2[r] - mn);
      m2[r] = mn;
      p0[r] = exp2f(sv[0][r] - mn);
      p1[r] = exp2f(sv[1][r] - mn);
      ls[r] = ls[r] * sca + p0[r] + p1[r];
#pragma unroll
      for (int n = 0; n < 8; n++) acc[n][r] *= sca;
    }
#pragma unroll
    for (int r = 0; r < 4; r++) {
      P[(4 * g + r) * 40 + lq] = f2bf(p0[r]);
      P[(4 * g + r) * 40 + 16 + lq] = f2bf(p1[r]);
    }
    short8 pa = *(const short8*)(P + lq * 40 + g * 8);
#pragma unroll
    for (int n = 0; n < 8; n++) {
      short8 vf = *(const short8*)(vp + (size_t)(n * 16 + lq) * T_SEQ + kv0 + g * 8);
      acc[n] = __builtin_amdgcn_mfma_f32_16x16x32_bf16(pa, vf, acc[n], 0, 0, 0);
    }
  }
#pragma unroll
  for (int off = 1; off < 16; off <<= 1)
#pragma unroll
    for (int r = 0; r < 4; r++) ls[r] += __shfl_xor(ls[r], off);
  float inv[4];
#pragma unroll
  for (int r = 0; r < 4; r++) inv[r] = 1.f / ls[r];
  u16* cp = CTX + ((size_t)b * T_SEQ + q0) * E_DIM + h * D_HEAD;
#pragma unroll
  for (int n = 0; n < 8; n++)
#pragma unroll
    for (int r = 0; r < 4; r++)
      cp[(size_t)(4 * g + r) * E_DIM + n * 16 + lq] = f2bf(acc[n][r] * inv[r]);
}

extern "C" void kernel_launch(void* const* d_in, const int* in_sizes, int n_in,
                              void* d_out, int out_size, void* d_ws, size_t ws_size,
                              hipStream_t stream) {
  (void)in_sizes; (void)n_in; (void)out_size; (void)ws_size;
  const float* x  = (const float*)d_in[0];
  const float* g1 = (const float*)d_in[1];
  const float* b1 = (const float*)d_in[2];
  const float* wq = (const float*)d_in[3];
  const float* wk = (const float*)d_in[4];
  const float* wv = (const float*)d_in[5];
  const float* wo = (const float*)d_in[6];
  const float* g2 = (const float*)d_in[7];
  const float* b2 = (const float*)d_in[8];
  const float* w1 = (const float*)d_in[9];
  const float* w2 = (const float*)d_in[10];
  const float* w3 = (const float*)d_in[11];
  float* out = (float*)d_out;

  const size_t EE2 = (size_t)E_DIM * E_DIM * 2;
  const size_t EF2 = (size_t)E_DIM * FFN_DIM * 2;
  const size_t ME2 = (size_t)M_ROWS * E_DIM * 2;
  char* p = (char*)d_ws;
  u16* wqT = (u16*)p; p += EE2;
  u16* wkT = (u16*)p; p += EE2;
  u16* wvT = (u16*)p; p += EE2;
  u16* woT = (u16*)p; p += EE2;
  u16* w1T = (u16*)p; p += EF2;
  u16* w2T = (u16*)p; p += EF2;
  u16* w3T = (u16*)p; p += EF2;
  u16* Hb  = (u16*)p; p += ME2;
  u16* Qb  = (u16*)p; p += ME2;
  u16* Kbf = (u16*)p; p += ME2;
  u16* Vb  = (u16*)p; p += ME2;
  u16* VTb = (u16*)p; p += ME2;
  u16* CTXb = (u16*)p; p += ME2;
  u16* U1b = Qb;  // u1/gated (67MB) reuses dead q/k/v/vT region

  dim3 blk32(32, 8);
  // weights -> bf16 transposed [N][K]
  cvt_t_kernel<<<dim3(E_DIM / 32, E_DIM / 32), blk32, 0, stream>>>(wq, wqT, E_DIM, E_DIM);
  cvt_t_kernel<<<dim3(E_DIM / 32, E_DIM / 32), blk32, 0, stream>>>(wk, wkT, E_DIM, E_DIM);
  cvt_t_kernel<<<dim3(E_DIM / 32, E_DIM / 32), blk32, 0, stream>>>(wv, wvT, E_DIM, E_DIM);
  cvt_t_kernel<<<dim3(E_DIM / 32, E_DIM / 32), blk32, 0, stream>>>(wo, woT, E_DIM, E_DIM);
  cvt_t_kernel<<<dim3(FFN_DIM / 32, E_DIM / 32), blk32, 0, stream>>>(w1, w1T, E_DIM, FFN_DIM);
  cvt_t_kernel<<<dim3(FFN_DIM / 32, E_DIM / 32), blk32, 0, stream>>>(w2, w2T, E_DIM, FFN_DIM);
  cvt_t_kernel<<<dim3(E_DIM / 32, FFN_DIM / 32), blk32, 0, stream>>>(w3, w3T, FFN_DIM, E_DIM);

  // attention block
  ln_kernel<<<M_ROWS, 256, 0, stream>>>(x, g1, b1, Hb);
  gemm_bt<0><<<dim3(E_DIM / 128, M_ROWS / 128), 256, 0, stream>>>(Hb, wqT, Qb, nullptr, E_DIM, E_DIM);
  gemm_bt<0><<<dim3(E_DIM / 128, M_ROWS / 128), 256, 0, stream>>>(Hb, wkT, Kbf, nullptr, E_DIM, E_DIM);
  gemm_bt<0><<<dim3(E_DIM / 128, M_ROWS / 128), 256, 0, stream>>>(Hb, wvT, Vb, nullptr, E_DIM, E_DIM);
  transpose_v_kernel<<<dim3(T_SEQ / 32, E_DIM / 32, 2), blk32, 0, stream>>>(Vb, VTb);
  attn_kernel<<<dim3(T_SEQ / 64, 2 * N_HEAD), 256, 0, stream>>>(Qb, Kbf, VTb, CTXb);
  gemm_bt<1><<<dim3(E_DIM / 128, M_ROWS / 128), 256, 0, stream>>>(CTXb, woT, out, x, E_DIM, E_DIM);

  // SwiGLU MLP block
  ln_kernel<<<M_ROWS, 256, 0, stream>>>(out, g2, b2, Hb);
  gemm_bt<0><<<dim3(FFN_DIM / 128, M_ROWS / 128), 256, 0, stream>>>(Hb, w1T, U1b, nullptr, FFN_DIM, E_DIM);
  gemm_bt<2><<<dim3(FFN_DIM / 128, M_ROWS / 128), 256, 0, stream>>>(Hb, w2T, U1b, U1b, FFN_DIM, E_DIM);
  gemm_bt<1><<<dim3(E_DIM / 128, M_ROWS / 128), 256, 0, stream>>>(U1b, w3T, out, out, E_DIM, FFN_DIM);
}

// Round 2
// 1048.882 us; speedup vs baseline: 1.2794x; 1.2794x over previous
//
#include <hip/hip_runtime.h>

// Transformer layer, bf16 MFMA compute, fp32 I/O.
// B=2 T=2048 E=2048 H=16 DH=128 FFN=8192. Needs ~235MB workspace.

#define T_SEQ 2048
#define E_DIM 2048
#define N_HEAD 16
#define D_HEAD 128
#define FFN_DIM 8192
#define M_ROWS 4096  // B*T

typedef unsigned short u16;
typedef short short8 __attribute__((ext_vector_type(8)));
typedef float f32x4 __attribute__((ext_vector_type(4)));

#define DEV __device__ __forceinline__

DEV u16 f2bf(float f) {
  unsigned u = __float_as_uint(f);
  u += 0x7fffu + ((u >> 16) & 1u);
  return (u16)(u >> 16);
}
DEV float bf2f(u16 h) { return __uint_as_float(((unsigned)h) << 16); }

DEV void async16(void* lds, const void* g) {
  __builtin_amdgcn_global_load_lds((const __attribute__((address_space(1))) void*)g,
                                   (__attribute__((address_space(3))) void*)lds, 16, 0, 0);
}

// ---------------- LayerNorm: fp32 [rows][E] -> bf16 -----------------
__global__ __launch_bounds__(256) void ln_kernel(const float* __restrict__ x,
                                                 const float* __restrict__ gw,
                                                 const float* __restrict__ bw,
                                                 u16* __restrict__ out) {
  int row = blockIdx.x;
  int t = threadIdx.x;
  const float4* xr = (const float4*)(x + (size_t)row * E_DIM);
  float4 a = xr[t], c = xr[t + 256];
  float s = a.x + a.y + a.z + a.w + c.x + c.y + c.z + c.w;
  float q = a.x * a.x + a.y * a.y + a.z * a.z + a.w * a.w +
            c.x * c.x + c.y * c.y + c.z * c.z + c.w * c.w;
  for (int off = 32; off > 0; off >>= 1) {
    s += __shfl_down(s, off);
    q += __shfl_down(q, off);
  }
  __shared__ float red[8];
  if ((t & 63) == 0) { red[(t >> 6) * 2] = s; red[(t >> 6) * 2 + 1] = q; }
  __syncthreads();
  s = red[0] + red[2] + red[4] + red[6];
  q = red[1] + red[3] + red[5] + red[7];
  float mu = s * (1.f / E_DIM);
  float rs = rsqrtf(q * (1.f / E_DIM) - mu * mu + 1e-5f);
  const float4* g4 = (const float4*)gw;
  const float4* b4 = (const float4*)bw;
  float4 g0 = g4[t], g1v = g4[t + 256], e0 = b4[t], e1 = b4[t + 256];
  ushort4 o0, o1;
  o0.x = f2bf((a.x - mu) * rs * g0.x + e0.x);
  o0.y = f2bf((a.y - mu) * rs * g0.y + e0.y);
  o0.z = f2bf((a.z - mu) * rs * g0.z + e0.z);
  o0.w = f2bf((a.w - mu) * rs * g0.w + e0.w);
  o1.x = f2bf((c.x - mu) * rs * g1v.x + e1.x);
  o1.y = f2bf((c.y - mu) * rs * g1v.y + e1.y);
  o1.z = f2bf((c.z - mu) * rs * g1v.z + e1.z);
  o1.w = f2bf((c.w - mu) * rs * g1v.w + e1.w);
  ((ushort4*)(out + (size_t)row * E_DIM))[t] = o0;
  ((ushort4*)(out + (size_t)row * E_DIM))[t + 256] = o1;
}

// ------- convert+transpose: fp32 W[K][N] -> bf16 WT[N][K] -----------
__global__ __launch_bounds__(256) void cvt_t_kernel(const float* __restrict__ W,
                                                    u16* __restrict__ WT,
                                                    int Kd, int Nd) {
  __shared__ float tile[32][33];
  int tx = threadIdx.x, ty = threadIdx.y;
  int n0 = blockIdx.x * 32, k0 = blockIdx.y * 32;
#pragma unroll
  for (int i = 0; i < 4; i++)
    tile[ty + i * 8][tx] = W[(size_t)(k0 + ty + i * 8) * Nd + n0 + tx];
  __syncthreads();
#pragma unroll
  for (int i = 0; i < 4; i++)
    WT[(size_t)(n0 + ty + i * 8) * Kd + k0 + tx] = f2bf(tile[tx][ty + i * 8]);
}

// ------- transpose V per batch: bf16 [B*T][E] -> [B][E][T] ----------
__global__ __launch_bounds__(256) void transpose_v_kernel(const u16* __restrict__ v,
                                                          u16* __restrict__ vt) {
  __shared__ u16 tile[32][33];
  int tx = threadIdx.x, ty = threadIdx.y;
  int b = blockIdx.z;
  int t0 = blockIdx.x * 32, e0 = blockIdx.y * 32;
#pragma unroll
  for (int i = 0; i < 4; i++)
    tile[ty + i * 8][tx] = v[(size_t)(b * T_SEQ + t0 + ty + i * 8) * E_DIM + e0 + tx];
  __syncthreads();
#pragma unroll
  for (int i = 0; i < 4; i++)
    vt[((size_t)b * E_DIM + e0 + ty + i * 8) * T_SEQ + t0 + tx] = tile[tx][ty + i * 8];
}

// ----------------- GEMM: C[M][N] = A[M][K] * BT[N][K]^T -------------
// MODE 0: write bf16 C.
// MODE 1: Cout(float) = Extra(float resid) + acc.
// MODE 2: Cout(bf16)  = silu(Extra bf16) * acc   (SwiGLU; Extra may alias Cout)
template <int MODE>
__global__ __launch_bounds__(256, 2) void gemm_bt(const u16* __restrict__ A,
                                                  const u16* __restrict__ BT,
                                                  void* Cout, const void* Extra,
                                                  int N, int K) {
  __shared__ u16 As[128 * 32];
  __shared__ u16 Bs[128 * 32];
  const int t = threadIdx.x;
  const int l = t & 63, w = t >> 6;
  const int wr = w >> 1, wc = w & 1;
  const int lq = l & 15, g = l >> 4;
  const size_t bm = (size_t)blockIdx.y * 128, bn = (size_t)blockIdx.x * 128;

  const u16* Ap = A + (bm + (t >> 2)) * (size_t)K + (t & 3) * 8;
  const u16* Bp = BT + (bn + (t >> 2)) * (size_t)K + (t & 3) * 8;
  u16* as_dst = As + w * 512;  // wave-uniform; HW adds lane*16B
  u16* bs_dst = Bs + w * 512;

  f32x4 acc[4][4] = {};

  for (int k0 = 0; k0 < K; k0 += 32) {
    async16(as_dst, Ap + k0);
    async16(as_dst + 2048, Ap + (size_t)64 * K + k0);
    async16(bs_dst, Bp + k0);
    async16(bs_dst + 2048, Bp + (size_t)64 * K + k0);
    __syncthreads();
    short8 af[4], bf[4];
#pragma unroll
    for (int m = 0; m < 4; m++)
      af[m] = *(const short8*)(As + (wr * 64 + m * 16 + lq) * 32 + g * 8);
#pragma unroll
    for (int n = 0; n < 4; n++)
      bf[n] = *(const short8*)(Bs + (wc * 64 + n * 16 + lq) * 32 + g * 8);
#pragma unroll
    for (int m = 0; m < 4; m++)
#pragma unroll
      for (int n = 0; n < 4; n++)
        acc[m][n] = __builtin_amdgcn_mfma_f32_16x16x32_bf16(af[m], bf[n], acc[m][n], 0, 0, 0);
    __syncthreads();
  }

#pragma unroll
  for (int m = 0; m < 4; m++) {
    size_t row = bm + wr * 64 + m * 16 + 4 * g;
#pragma unroll
    for (int n = 0; n < 4; n++) {
      size_t col = bn + wc * 64 + n * 16 + lq;
#pragma unroll
      for (int r = 0; r < 4; r++) {
        size_t idx = (row + r) * (size_t)N + col;
        if constexpr (MODE == 0) {
          ((u16*)Cout)[idx] = f2bf(acc[m][n][r]);
        } else if constexpr (MODE == 1) {
          ((float*)Cout)[idx] = ((const float*)Extra)[idx] + acc[m][n][r];
        } else {
          float a = bf2f(((const u16*)Extra)[idx]);
          float sil = a / (1.f + exp2f(-1.4426950408889634f * a));
          ((u16*)Cout)[idx] = f2bf(sil * acc[m][n][r]);
        }
      }
    }
  }
}

// ----------------- causal flash attention (LDS-staged) --------------
// grid (T/64, B*H); 4 waves/block; block owns 64 q-rows of one (b,h);
// wave w owns rows q0blk + 16w .. +16.  KV tile = 64.
// K tile [64][128] and V^T tile [128][64] staged in LDS via
// global_load_lds (linear dest) with XOR-swizzled global source
// (chunk ^= row&7); reads apply the same XOR -> ~2-way conflicts.
__global__ __launch_bounds__(256, 3) void attn_kernel(const u16* __restrict__ Q,
                                                      const u16* __restrict__ Kb,
                                                      const u16* __restrict__ VT,
                                                      u16* __restrict__ CTX) {
  __shared__ u16 Ks[64 * 128];    // 16 KB
  __shared__ u16 Vs[128 * 64];    // 16 KB
  __shared__ u16 P_all[4][16 * 72];  // 9 KB, per-wave padded P tile
  const int t = threadIdx.x;
  const int w = t >> 6, l = t & 63, g = l >> 4, lq = l & 15;
  u16* P = P_all[w];
  const int q0blk = blockIdx.x * 64;
  const int q0w = q0blk + w * 16;
  const int bh = blockIdx.y, b = bh >> 4, h = bh & 15;
  const u16* qp = Q + (size_t)b * T_SEQ * E_DIM + h * D_HEAD;
  const u16* kp = Kb + (size_t)b * T_SEQ * E_DIM + h * D_HEAD;
  const u16* vp = VT + ((size_t)b * E_DIM + h * D_HEAD) * T_SEQ;

  short8 qf[4];
#pragma unroll
  for (int ks = 0; ks < 4; ks++)
    qf[ks] = *(const short8*)(qp + (size_t)(q0w + lq) * E_DIM + ks * 32 + g * 8);

  f32x4 acc[8] = {};
  float m2[4], ls[4];
#pragma unroll
  for (int r = 0; r < 4; r++) { m2[r] = -1e30f; ls[r] = 0.f; }
  const float sc = 0.08838834764831845f * 1.4426950408889634f;  // 1/sqrt(128)*log2e

  // staging lane decomposition (constant per thread)
  const int kRow0 = 16 * w + (l >> 4);        // + 4*j rows; chunk = l&15
  const int kChunk = l & 15;
  const int vRow0 = 32 * w + (l >> 3);        // + 8*j rows; chunk = l&7
  const int vChunk = l & 7;

  for (int kv0 = 0; kv0 <= q0blk; kv0 += 64) {
    // ---- stage K tile [64][128] : wave w stages rows 16w..16w+15 ----
#pragma unroll
    for (int j = 0; j < 4; j++) {
      int R = kRow0 + 4 * j;
      async16(Ks + (16 * w + 4 * j) * 128,
              kp + (size_t)(kv0 + R) * E_DIM + ((kChunk ^ (R & 7)) << 3));
    }
    // ---- stage V^T tile [128][64] : wave w stages rows 32w..32w+31 --
#pragma unroll
    for (int j = 0; j < 4; j++) {
      int D = vRow0 + 8 * j;
      async16(Vs + (32 * w + 8 * j) * 64,
              vp + (size_t)D * T_SEQ + kv0 + ((vChunk ^ (D & 7)) << 3));
    }
    __syncthreads();

    // ---- QK^T : 4 col-subtiles of 16 ----
    f32x4 s[4];
#pragma unroll
    for (int ct = 0; ct < 4; ct++) {
      s[ct] = f32x4{0.f, 0.f, 0.f, 0.f};
#pragma unroll
      for (int ks = 0; ks < 4; ks++) {
        short8 kf = *(const short8*)(Ks + (ct * 16 + lq) * 128 +
                                     (((ks * 4 + g) ^ (lq & 7)) << 3));
        s[ct] = __builtin_amdgcn_mfma_f32_16x16x32_bf16(qf[ks], kf, s[ct], 0, 0, 0);
      }
    }
    float sv[4][4];
#pragma unroll
    for (int ct = 0; ct < 4; ct++)
#pragma unroll
      for (int r = 0; r < 4; r++) sv[ct][r] = s[ct][r] * sc;
    if (kv0 + 64 > q0w) {  // tile touches the diagonal: mask kv > q
#pragma unroll
      for (int ct = 0; ct < 4; ct++)
#pragma unroll
        for (int r = 0; r < 4; r++)
          if (kv0 + ct * 16 + lq > q0w + 4 * g + r) sv[ct][r] = -1e30f;
    }
    float mx[4];
#pragma unroll
    for (int r = 0; r < 4; r++)
      mx[r] = fmaxf(fmaxf(sv[0][r], sv[1][r]), fmaxf(sv[2][r], sv[3][r]));
#pragma unroll
    for (int off = 1; off < 16; off <<= 1)
#pragma unroll
      for (int r = 0; r < 4; r++) mx[r] = fmaxf(mx[r], __shfl_xor(mx[r], off));
#pragma unroll
    for (int r = 0; r < 4; r++) {
      float mn = fmaxf(m2[r], mx[r]);
      float sca = exp2f(m2[r] - mn);
      m2[r] = mn;
      float sum = 0.f;
#pragma unroll
      for (int ct = 0; ct < 4; ct++) {
        float pv = exp2f(sv[ct][r] - mn);
        sum += pv;
        P[(4 * g + r) * 72 + ct * 16 + lq] = f2bf(pv);
      }
      ls[r] = ls[r] * sca + sum;
#pragma unroll
      for (int n = 0; n < 8; n++) acc[n][r] *= sca;
    }
    short8 pa[2];
#pragma unroll
    for (int ks2 = 0; ks2 < 2; ks2++)
      pa[ks2] = *(const short8*)(P + lq * 72 + ks2 * 32 + g * 8);
    // ---- PV : 8 d-subtiles x 2 k-slices ----
#pragma unroll
    for (int n = 0; n < 8; n++)
#pragma unroll
      for (int ks2 = 0; ks2 < 2; ks2++) {
        short8 vf = *(const short8*)(Vs + (n * 16 + lq) * 64 +
                                     (((ks2 * 4 + g) ^ (lq & 7)) << 3));
        acc[n] = __builtin_amdgcn_mfma_f32_16x16x32_bf16(pa[ks2], vf, acc[n], 0, 0, 0);
      }
    __syncthreads();
  }

#pragma unroll
  for (int off = 1; off < 16; off <<= 1)
#pragma unroll
    for (int r = 0; r < 4; r++) ls[r] += __shfl_xor(ls[r], off);
  float inv[4];
#pragma unroll
  for (int r = 0; r < 4; r++) inv[r] = 1.f / ls[r];
  u16* cp = CTX + ((size_t)b * T_SEQ + q0w) * E_DIM + h * D_HEAD;
#pragma unroll
  for (int n = 0; n < 8; n++)
#pragma unroll
    for (int r = 0; r < 4; r++)
      cp[(size_t)(4 * g + r) * E_DIM + n * 16 + lq] = f2bf(acc[n][r] * inv[r]);
}

extern "C" void kernel_launch(void* const* d_in, const int* in_sizes, int n_in,
                              void* d_out, int out_size, void* d_ws, size_t ws_size,
                              hipStream_t stream) {
  (void)in_sizes; (void)n_in; (void)out_size; (void)ws_size;
  const float* x  = (const float*)d_in[0];
  const float* g1 = (const float*)d_in[1];
  const float* b1 = (const float*)d_in[2];
  const float* wq = (const float*)d_in[3];
  const float* wk = (const float*)d_in[4];
  const float* wv = (const float*)d_in[5];
  const float* wo = (const float*)d_in[6];
  const float* g2 = (const float*)d_in[7];
  const float* b2 = (const float*)d_in[8];
  const float* w1 = (const float*)d_in[9];
  const float* w2 = (const float*)d_in[10];
  const float* w3 = (const float*)d_in[11];
  float* out = (float*)d_out;

  const size_t EE2 = (size_t)E_DIM * E_DIM * 2;
  const size_t EF2 = (size_t)E_DIM * FFN_DIM * 2;
  const size_t ME2 = (size_t)M_ROWS * E_DIM * 2;
  char* p = (char*)d_ws;
  u16* wqT = (u16*)p; p += EE2;
  u16* wkT = (u16*)p; p += EE2;
  u16* wvT = (u16*)p; p += EE2;
  u16* woT = (u16*)p; p += EE2;
  u16* w1T = (u16*)p; p += EF2;
  u16* w2T = (u16*)p; p += EF2;
  u16* w3T = (u16*)p; p += EF2;
  u16* Hb  = (u16*)p; p += ME2;
  u16* Qb  = (u16*)p; p += ME2;
  u16* Kbf = (u16*)p; p += ME2;
  u16* Vb  = (u16*)p; p += ME2;
  u16* VTb = (u16*)p; p += ME2;
  u16* CTXb = (u16*)p; p += ME2;
  u16* U1b = Qb;  // u1/gated (67MB) reuses dead q/k/v/vT region

  dim3 blk32(32, 8);
  // weights -> bf16 transposed [N][K]
  cvt_t_kernel<<<dim3(E_DIM / 32, E_DIM / 32), blk32, 0, stream>>>(wq, wqT, E_DIM, E_DIM);
  cvt_t_kernel<<<dim3(E_DIM / 32, E_DIM / 32), blk32, 0, stream>>>(wk, wkT, E_DIM, E_DIM);
  cvt_t_kernel<<<dim3(E_DIM / 32, E_DIM / 32), blk32, 0, stream>>>(wv, wvT, E_DIM, E_DIM);
  cvt_t_kernel<<<dim3(E_DIM / 32, E_DIM / 32), blk32, 0, stream>>>(wo, woT, E_DIM, E_DIM);
  cvt_t_kernel<<<dim3(FFN_DIM / 32, E_DIM / 32), blk32, 0, stream>>>(w1, w1T, E_DIM, FFN_DIM);
  cvt_t_kernel<<<dim3(FFN_DIM / 32, E_DIM / 32), blk32, 0, stream>>>(w2, w2T, E_DIM, FFN_DIM);
  cvt_t_kernel<<<dim3(E_DIM / 32, FFN_DIM / 32), blk32, 0, stream>>>(w3, w3T, FFN_DIM, E_DIM);

  // attention block
  ln_kernel<<<M_ROWS, 256, 0, stream>>>(x, g1, b1, Hb);
  gemm_bt<0><<<dim3(E_DIM / 128, M_ROWS / 128), 256, 0, stream>>>(Hb, wqT, Qb, nullptr, E_DIM, E_DIM);
  gemm_bt<0><<<dim3(E_DIM / 128, M_ROWS / 128), 256, 0, stream>>>(Hb, wkT, Kbf, nullptr, E_DIM, E_DIM);
  gemm_bt<0><<<dim3(E_DIM / 128, M_ROWS / 128), 256, 0, stream>>>(Hb, wvT, Vb, nullptr, E_DIM, E_DIM);
  transpose_v_kernel<<<dim3(T_SEQ / 32, E_DIM / 32, 2), blk32, 0, stream>>>(Vb, VTb);
  attn_kernel<<<dim3(T_SEQ / 64, 2 * N_HEAD), 256, 0, stream>>>(Qb, Kbf, VTb, CTXb);
  gemm_bt<1><<<dim3(E_DIM / 128, M_ROWS / 128), 256, 0, stream>>>(CTXb, woT, out, x, E_DIM, E_DIM);

  // SwiGLU MLP block
  ln_kernel<<<M_ROWS, 256, 0, stream>>>(out, g2, b2, Hb);
  gemm_bt<0><<<dim3(FFN_DIM / 128, M_ROWS / 128), 256, 0, stream>>>(Hb, w1T, U1b, nullptr, FFN_DIM, E_DIM);
  gemm_bt<2><<<dim3(FFN_DIM / 128, M_ROWS / 128), 256, 0, stream>>>(Hb, w2T, U1b, U1b, FFN_DIM, E_DIM);
  gemm_bt<1><<<dim3(E_DIM / 128, M_ROWS / 128), 256, 0, stream>>>(U1b, w3T, out, out, E_DIM, FFN_DIM);
}